// Round 7
// baseline (166.067 us; speedup 1.0000x reference)
//
#include <hip/hip_runtime.h>
#include <math.h>

#define Bb 64
#define BG 32            // batches per group (2 groups: working set 134 MB < 256 MiB MALL)
#define NGROUPS 2
#define Nn 8192
#define Mm 128
#define EPSf 1e-16f
#define COS_EPSf 1e-8f

typedef __attribute__((ext_vector_type(4))) float f32x4;

// ---------------- Kernel A: content-addressing scores ----------------
// 16 lanes per row, 2x float4 per lane. 128 rows per block (SITERS=8, R5-proven).
// Batch offset handled by pointer offsets from host.
#define SITERS 8
__global__ __launch_bounds__(256) void score_kernel(
    const float* __restrict__ memory, const float* __restrict__ k,
    const float* __restrict__ beta, float* score /* aliases w section */) {
  const int b = blockIdx.y;      // batch within group
  const int tid = threadIdx.x;
  const int q = tid & 15;
  const int rsub = tid >> 4;
  const int row0 = blockIdx.x * (16 * SITERS);
  const size_t bbase = (size_t)b * Nn;

  const f32x4 ka = *(const f32x4*)(k + b * Mm + q * 4);
  const f32x4 kb = *(const f32x4*)(k + b * Mm + 64 + q * 4);
  float kf[8];
#pragma unroll
  for (int j = 0; j < 4; j++) { kf[j] = ka[j] + EPSf; kf[4 + j] = kb[j] + EPSf; }
  float sqk = 0.f;
#pragma unroll
  for (int j = 0; j < 8; j++) sqk += kf[j] * kf[j];
  sqk += __shfl_xor(sqk, 1); sqk += __shfl_xor(sqk, 2);
  sqk += __shfl_xor(sqk, 4); sqk += __shfl_xor(sqk, 8);
  const float bscale = beta[b] / fmaxf(sqrtf(sqk), COS_EPSf);

#pragma unroll 8
  for (int it = 0; it < SITERS; it++) {
    const int row = row0 + it * 16 + rsub;
    const float* rp = memory + (bbase + row) * Mm;
    const f32x4 ma = *(const f32x4*)(rp + q * 4);
    const f32x4 mb = *(const f32x4*)(rp + 64 + q * 4);
    float dot = 0.f, sqm = 0.f;
#pragma unroll
    for (int j = 0; j < 4; j++) {
      const float m0 = ma[j] + EPSf, m1 = mb[j] + EPSf;
      dot = fmaf(m0, kf[j], dot); dot = fmaf(m1, kf[4 + j], dot);
      sqm = fmaf(m0, m0, sqm);    sqm = fmaf(m1, m1, sqm);
    }
    dot += __shfl_xor(dot, 1); sqm += __shfl_xor(sqm, 1);
    dot += __shfl_xor(dot, 2); sqm += __shfl_xor(sqm, 2);
    dot += __shfl_xor(dot, 4); sqm += __shfl_xor(sqm, 4);
    dot += __shfl_xor(dot, 8); sqm += __shfl_xor(sqm, 8);
    if (q == 0) score[bbase + row] = bscale * dot / fmaxf(sqrtf(sqm), COS_EPSf);
  }
}

// ---------------- Kernel B: softmax + gate + circular shift + sharpen ----------------
__device__ __forceinline__ float block_sum16(float v, float* scratch) {
  const int lane = threadIdx.x & 63, wid = threadIdx.x >> 6;
  for (int o = 32; o; o >>= 1) v += __shfl_down(v, o);
  if (lane == 0) scratch[wid] = v;
  __syncthreads();
  if (threadIdx.x < 16) {
    v = scratch[threadIdx.x];
    for (int o = 8; o; o >>= 1) v += __shfl_down(v, o);
    if (threadIdx.x == 0) scratch[0] = v;
  }
  __syncthreads();
  v = scratch[0];
  __syncthreads();
  return v;
}

__device__ __forceinline__ float block_max16(float v, float* scratch) {
  const int lane = threadIdx.x & 63, wid = threadIdx.x >> 6;
  for (int o = 32; o; o >>= 1) v = fmaxf(v, __shfl_down(v, o));
  if (lane == 0) scratch[wid] = v;
  __syncthreads();
  if (threadIdx.x < 16) {
    v = scratch[threadIdx.x];
    for (int o = 8; o; o >>= 1) v = fmaxf(v, __shfl_down(v, o));
    if (threadIdx.x == 0) scratch[0] = v;
  }
  __syncthreads();
  v = scratch[0];
  __syncthreads();
  return v;
}

__global__ __launch_bounds__(1024) void weight_kernel(
    const float* score,                    // aliases w_out — all reads precede writes
    const float* __restrict__ w_prev, const float* __restrict__ g,
    const float* __restrict__ s, const float* __restrict__ gamma,
    float* w_out) {
  __shared__ float wg[Nn];
  __shared__ float scratch[16];
  const int b = blockIdx.x;      // batch within group
  const int tid = threadIdx.x;
  const int PT = Nn / 1024;

  float sc[PT];
  float lmax = -INFINITY;
#pragma unroll
  for (int i = 0; i < PT; i++) {
    sc[i] = score[b * Nn + tid + i * 1024];
    lmax = fmaxf(lmax, sc[i]);
  }
  const float bmax = block_max16(lmax, scratch);

  float lsum = 0.f;
#pragma unroll
  for (int i = 0; i < PT; i++) {
    sc[i] = __expf(sc[i] - bmax);
    lsum += sc[i];
  }
  const float Z = block_sum16(lsum, scratch);
  const float invZ = 1.f / Z;

  const float gb = g[b];
  const float s0 = s[b * 3 + 0], s1 = s[b * 3 + 1], s2 = s[b * 3 + 2];
  const float gam = gamma[b];

#pragma unroll
  for (int i = 0; i < PT; i++) {
    const int n = tid + i * 1024;
    const float wr = sc[i] * invZ;
    wg[n] = gb * wr + (1.f - gb) * w_prev[b * Nn + n];
  }
  __syncthreads();

  float wp[PT];
  float psum = 0.f;
#pragma unroll
  for (int i = 0; i < PT; i++) {
    const int n = tid + i * 1024;
    const float wsv = s0 * wg[(n + Nn - 1) & (Nn - 1)] + s1 * wg[n] + s2 * wg[(n + 1) & (Nn - 1)];
    wp[i] = __powf(wsv, gam);    // wsv > 0 (convex mix of positive weights)
    psum += wp[i];
  }
  const float S = block_sum16(psum, scratch) + EPSf;
  const float invS = 1.f / S;
#pragma unroll
  for (int i = 0; i < PT; i++) w_out[b * Nn + tid + i * 1024] = wp[i] * invS;
}

// ---------------- Kernel C: memory update + read partials ----------------
// NT stores (A/B-proven -25 us). Reverse block order within group.
// Per-group launch: grid = BG*32 blocks; reads should hit MALL (group working
// set 134 MB < 256 MiB, score(g) just populated it, NT writes don't evict).
template <bool ATOMIC>
__global__ __launch_bounds__(256) void rw_kernel(
    const float* __restrict__ memory, const float* __restrict__ w,
    const float* __restrict__ e, const float* __restrict__ a,
    float* __restrict__ new_memory, float* __restrict__ out) {
  const int CH = 256;
  const int rbid = (int)gridDim.x - 1 - (int)blockIdx.x;   // reverse order
  const int b = rbid >> 5;             // batch within group
  const int chunk = rbid & 31;
  const int tid = threadIdx.x;
  const int m4 = tid & 31;
  const int rowg = tid >> 5;

  const f32x4 e4 = *(const f32x4*)(e + b * Mm + m4 * 4);
  const f32x4 a4 = *(const f32x4*)(a + b * Mm + m4 * 4);
  f32x4 acc = {0.f, 0.f, 0.f, 0.f};
  const size_t bbase = (size_t)b * Nn;
  const int row0 = chunk * CH;

#pragma unroll 8
  for (int i = 0; i < CH / 8; i++) {
    const int n = row0 + i * 8 + rowg;
    const float wn = w[bbase + n];
    const f32x4 mv = *(const f32x4*)(memory + (bbase + n) * Mm + m4 * 4);
    const f32x4 nm = mv + wn * (a4 - e4 * mv);   // mv*(1-wn*e) + wn*a
    __builtin_nontemporal_store(nm, (f32x4*)(new_memory + (bbase + n) * Mm + m4 * 4));
    acc += wn * mv;
  }

  __shared__ f32x4 red[256];
  red[tid] = acc;
  __syncthreads();
  for (int sh = 128; sh >= 32; sh >>= 1) {
    if (tid < sh) {
      const f32x4 o = red[tid + sh];
      red[tid] += o;
    }
    __syncthreads();
  }
  if (tid < 32) {
    const f32x4 r = red[tid];
    if (ATOMIC) {
      atomicAdd(&out[b * Mm + tid * 4 + 0], r[0]);
      atomicAdd(&out[b * Mm + tid * 4 + 1], r[1]);
      atomicAdd(&out[b * Mm + tid * 4 + 2], r[2]);
      atomicAdd(&out[b * Mm + tid * 4 + 3], r[3]);
    } else {
      *(f32x4*)(out + ((size_t)(b * 32 + chunk) * Mm) + tid * 4) = r;
    }
  }
}

// ---------------- Kernel D: fold chunk partials -> read[b,m] (all batches) ----------------
__global__ __launch_bounds__(256) void reduce_read_kernel(
    const float* __restrict__ partial, float* __restrict__ readout) {
  const int t = blockIdx.x * 256 + threadIdx.x;  // [0, B*M)
  const int b = t >> 7, m = t & 127;
  const float* p = partial + (size_t)b * 32 * Mm + m;
  float sum = 0.f;
#pragma unroll
  for (int c = 0; c < 32; c++) sum += p[c * Mm];
  readout[t] = sum;
}

extern "C" void kernel_launch(void* const* d_in, const int* in_sizes, int n_in,
                              void* d_out, int out_size, void* d_ws, size_t ws_size,
                              hipStream_t stream) {
  const float* memory = (const float*)d_in[0];
  const float* k      = (const float*)d_in[1];
  const float* beta   = (const float*)d_in[2];
  const float* g      = (const float*)d_in[3];
  const float* s      = (const float*)d_in[4];
  const float* gamma  = (const float*)d_in[5];
  const float* w_prev = (const float*)d_in[6];
  const float* e      = (const float*)d_in[7];
  const float* a      = (const float*)d_in[8];

  float* out      = (float*)d_out;
  float* read_out = out;                       // B*M
  float* w_out    = out + Bb * Mm;             // B*N
  float* new_mem  = out + Bb * Mm + (size_t)Bb * Nn;  // B*N*M
  float* score    = w_out;                     // stash scores in w section
  float* partial  = (float*)d_ws;              // B*32*M floats = 1 MiB
  const size_t need = (size_t)Bb * 32 * Mm * sizeof(float);

  if (ws_size >= need) {
    // Grouped schedule: per group g, score -> weight -> rw; rw(g) re-reads the
    // 134 MB that score(g) just cached in MALL before score(g+1) evicts it.
    for (int grp = 0; grp < NGROUPS; grp++) {
      const size_t bo = (size_t)grp * BG;                 // batch offset
      const float* mem_g   = memory + bo * Nn * Mm;
      float*       nmem_g  = new_mem + bo * Nn * Mm;
      const float* k_g     = k + bo * Mm;
      const float* beta_g  = beta + bo;
      const float* g_g     = g + bo;
      const float* s_g     = s + bo * 3;
      const float* gam_g   = gamma + bo;
      const float* wprev_g = w_prev + bo * Nn;
      const float* e_g     = e + bo * Mm;
      const float* a_g     = a + bo * Mm;
      float*       w_g     = w_out + bo * Nn;
      float*       score_g = score + bo * Nn;
      float*       part_g  = partial + bo * 32 * Mm;

      dim3 sgrid(Nn / (16 * SITERS), BG);
      score_kernel<<<sgrid, 256, 0, stream>>>(mem_g, k_g, beta_g, score_g);
      weight_kernel<<<BG, 1024, 0, stream>>>(score_g, wprev_g, g_g, s_g, gam_g, w_g);
      rw_kernel<false><<<BG * 32, 256, 0, stream>>>(mem_g, w_g, e_g, a_g, nmem_g, part_g);
    }
    reduce_read_kernel<<<(Bb * Mm) / 256, 256, 0, stream>>>(partial, read_out);
  } else {
    // Fallback (ws too small): ungrouped, atomic read accumulation
    hipMemsetAsync(read_out, 0, (size_t)Bb * Mm * sizeof(float), stream);
    dim3 sgrid(Nn / (16 * SITERS), Bb);
    score_kernel<<<sgrid, 256, 0, stream>>>(memory, k, beta, score);
    weight_kernel<<<Bb, 1024, 0, stream>>>(score, w_prev, g, s, gamma, w_out);
    rw_kernel<true><<<Bb * 32, 256, 0, stream>>>(memory, w_out, e, a, new_mem, read_out);
  }
}

// Round 8
// 159.096 us; speedup vs baseline: 1.0438x; 1.0438x over previous
//
#include <hip/hip_runtime.h>
#include <math.h>

#define Bb 64
#define Nn 8192
#define Mm 128
#define EPSf 1e-16f
#define COS_EPSf 1e-8f

typedef __attribute__((ext_vector_type(4))) float f32x4;

// ---------------- Kernel A: content-addressing scores ----------------
// 16 lanes per row, 2x float4 per lane. 128 rows per block (SITERS=8, R5-proven).
#define SITERS 8
__global__ __launch_bounds__(256) void score_kernel(
    const float* __restrict__ memory, const float* __restrict__ k,
    const float* __restrict__ beta, float* score /* aliases w section */) {
  const int b = blockIdx.y;
  const int tid = threadIdx.x;
  const int q = tid & 15;
  const int rsub = tid >> 4;
  const int row0 = blockIdx.x * (16 * SITERS);
  const size_t bbase = (size_t)b * Nn;

  const f32x4 ka = *(const f32x4*)(k + b * Mm + q * 4);
  const f32x4 kb = *(const f32x4*)(k + b * Mm + 64 + q * 4);
  float kf[8];
#pragma unroll
  for (int j = 0; j < 4; j++) { kf[j] = ka[j] + EPSf; kf[4 + j] = kb[j] + EPSf; }
  float sqk = 0.f;
#pragma unroll
  for (int j = 0; j < 8; j++) sqk += kf[j] * kf[j];
  sqk += __shfl_xor(sqk, 1); sqk += __shfl_xor(sqk, 2);
  sqk += __shfl_xor(sqk, 4); sqk += __shfl_xor(sqk, 8);
  const float bscale = beta[b] / fmaxf(sqrtf(sqk), COS_EPSf);

#pragma unroll 8
  for (int it = 0; it < SITERS; it++) {
    const int row = row0 + it * 16 + rsub;
    const float* rp = memory + (bbase + row) * Mm;
    const f32x4 ma = *(const f32x4*)(rp + q * 4);
    const f32x4 mb = *(const f32x4*)(rp + 64 + q * 4);
    float dot = 0.f, sqm = 0.f;
#pragma unroll
    for (int j = 0; j < 4; j++) {
      const float m0 = ma[j] + EPSf, m1 = mb[j] + EPSf;
      dot = fmaf(m0, kf[j], dot); dot = fmaf(m1, kf[4 + j], dot);
      sqm = fmaf(m0, m0, sqm);    sqm = fmaf(m1, m1, sqm);
    }
    dot += __shfl_xor(dot, 1); sqm += __shfl_xor(sqm, 1);
    dot += __shfl_xor(dot, 2); sqm += __shfl_xor(sqm, 2);
    dot += __shfl_xor(dot, 4); sqm += __shfl_xor(sqm, 4);
    dot += __shfl_xor(dot, 8); sqm += __shfl_xor(sqm, 8);
    if (q == 0) score[bbase + row] = bscale * dot / fmaxf(sqrtf(sqm), COS_EPSf);
  }
}

// ---------------- Kernel B: softmax + gate + circular shift + sharpen ----------------
__device__ __forceinline__ float block_sum16(float v, float* scratch) {
  const int lane = threadIdx.x & 63, wid = threadIdx.x >> 6;
  for (int o = 32; o; o >>= 1) v += __shfl_down(v, o);
  if (lane == 0) scratch[wid] = v;
  __syncthreads();
  if (threadIdx.x < 16) {
    v = scratch[threadIdx.x];
    for (int o = 8; o; o >>= 1) v += __shfl_down(v, o);
    if (threadIdx.x == 0) scratch[0] = v;
  }
  __syncthreads();
  v = scratch[0];
  __syncthreads();
  return v;
}

__device__ __forceinline__ float block_max16(float v, float* scratch) {
  const int lane = threadIdx.x & 63, wid = threadIdx.x >> 6;
  for (int o = 32; o; o >>= 1) v = fmaxf(v, __shfl_down(v, o));
  if (lane == 0) scratch[wid] = v;
  __syncthreads();
  if (threadIdx.x < 16) {
    v = scratch[threadIdx.x];
    for (int o = 8; o; o >>= 1) v = fmaxf(v, __shfl_down(v, o));
    if (threadIdx.x == 0) scratch[0] = v;
  }
  __syncthreads();
  v = scratch[0];
  __syncthreads();
  return v;
}

__global__ __launch_bounds__(1024) void weight_kernel(
    const float* score,                    // aliases w_out — all reads precede writes
    const float* __restrict__ w_prev, const float* __restrict__ g,
    const float* __restrict__ s, const float* __restrict__ gamma,
    float* w_out) {
  __shared__ float wg[Nn];
  __shared__ float scratch[16];
  const int b = blockIdx.x;
  const int tid = threadIdx.x;
  const int PT = Nn / 1024;

  float sc[PT];
  float lmax = -INFINITY;
#pragma unroll
  for (int i = 0; i < PT; i++) {
    sc[i] = score[b * Nn + tid + i * 1024];
    lmax = fmaxf(lmax, sc[i]);
  }
  const float bmax = block_max16(lmax, scratch);

  float lsum = 0.f;
#pragma unroll
  for (int i = 0; i < PT; i++) {
    sc[i] = __expf(sc[i] - bmax);
    lsum += sc[i];
  }
  const float Z = block_sum16(lsum, scratch);
  const float invZ = 1.f / Z;

  const float gb = g[b];
  const float s0 = s[b * 3 + 0], s1 = s[b * 3 + 1], s2 = s[b * 3 + 2];
  const float gam = gamma[b];

#pragma unroll
  for (int i = 0; i < PT; i++) {
    const int n = tid + i * 1024;
    const float wr = sc[i] * invZ;
    wg[n] = gb * wr + (1.f - gb) * w_prev[b * Nn + n];
  }
  __syncthreads();

  float wp[PT];
  float psum = 0.f;
#pragma unroll
  for (int i = 0; i < PT; i++) {
    const int n = tid + i * 1024;
    const float wsv = s0 * wg[(n + Nn - 1) & (Nn - 1)] + s1 * wg[n] + s2 * wg[(n + 1) & (Nn - 1)];
    wp[i] = __powf(wsv, gam);    // wsv > 0 (convex mix of positive weights)
    psum += wp[i];
  }
  const float S = block_sum16(psum, scratch) + EPSf;
  const float invS = 1.f / S;
#pragma unroll
  for (int i = 0; i < PT; i++) w_out[b * Nn + tid + i * 1024] = wp[i] * invS;
}

// ---------------- Kernel C: memory update + read partials ----------------
// NT stores (A/B-proven -25 us). NEW: NT loads for `memory` — last use of each
// line; 268 MB stream must not allocate in L2/MALL (guaranteed-waste evictions
// against the NT write stream; leaves L2 to the 2 MB w broadcast reads).
// Reverse block order retained (R5: -2 us).
template <bool ATOMIC>
__global__ __launch_bounds__(256) void rw_kernel(
    const float* __restrict__ memory, const float* __restrict__ w,
    const float* __restrict__ e, const float* __restrict__ a,
    float* __restrict__ new_memory, float* __restrict__ out) {
  const int CH = 256;
  const int rbid = (int)gridDim.x - 1 - (int)blockIdx.x;   // reverse order
  const int b = rbid >> 5;             // 32 chunks per batch
  const int chunk = rbid & 31;
  const int tid = threadIdx.x;
  const int m4 = tid & 31;
  const int rowg = tid >> 5;

  const f32x4 e4 = *(const f32x4*)(e + b * Mm + m4 * 4);
  const f32x4 a4 = *(const f32x4*)(a + b * Mm + m4 * 4);
  f32x4 acc = {0.f, 0.f, 0.f, 0.f};
  const size_t bbase = (size_t)b * Nn;
  const int row0 = chunk * CH;

#pragma unroll 8
  for (int i = 0; i < CH / 8; i++) {
    const int n = row0 + i * 8 + rowg;
    const float wn = w[bbase + n];
    const f32x4 mv = __builtin_nontemporal_load(
        (const f32x4*)(memory + (bbase + n) * Mm + m4 * 4));
    const f32x4 nm = mv + wn * (a4 - e4 * mv);   // mv*(1-wn*e) + wn*a
    __builtin_nontemporal_store(nm, (f32x4*)(new_memory + (bbase + n) * Mm + m4 * 4));
    acc += wn * mv;
  }

  __shared__ f32x4 red[256];
  red[tid] = acc;
  __syncthreads();
  for (int sh = 128; sh >= 32; sh >>= 1) {
    if (tid < sh) {
      const f32x4 o = red[tid + sh];
      red[tid] += o;
    }
    __syncthreads();
  }
  if (tid < 32) {
    const f32x4 r = red[tid];
    if (ATOMIC) {
      atomicAdd(&out[b * Mm + tid * 4 + 0], r[0]);
      atomicAdd(&out[b * Mm + tid * 4 + 1], r[1]);
      atomicAdd(&out[b * Mm + tid * 4 + 2], r[2]);
      atomicAdd(&out[b * Mm + tid * 4 + 3], r[3]);
    } else {
      *(f32x4*)(out + ((size_t)(b * 32 + chunk) * Mm) + tid * 4) = r;
    }
  }
}

// ---------------- Kernel D: fold chunk partials -> read[b,m] ----------------
__global__ __launch_bounds__(256) void reduce_read_kernel(
    const float* __restrict__ partial, float* __restrict__ readout) {
  const int t = blockIdx.x * 256 + threadIdx.x;  // [0, B*M)
  const int b = t >> 7, m = t & 127;
  const float* p = partial + (size_t)b * 32 * Mm + m;
  float sum = 0.f;
#pragma unroll
  for (int c = 0; c < 32; c++) sum += p[c * Mm];
  readout[t] = sum;
}

extern "C" void kernel_launch(void* const* d_in, const int* in_sizes, int n_in,
                              void* d_out, int out_size, void* d_ws, size_t ws_size,
                              hipStream_t stream) {
  const float* memory = (const float*)d_in[0];
  const float* k      = (const float*)d_in[1];
  const float* beta   = (const float*)d_in[2];
  const float* g      = (const float*)d_in[3];
  const float* s      = (const float*)d_in[4];
  const float* gamma  = (const float*)d_in[5];
  const float* w_prev = (const float*)d_in[6];
  const float* e      = (const float*)d_in[7];
  const float* a      = (const float*)d_in[8];

  float* out      = (float*)d_out;
  float* read_out = out;                       // B*M
  float* w_out    = out + Bb * Mm;             // B*N
  float* new_mem  = out + Bb * Mm + (size_t)Bb * Nn;  // B*N*M
  float* score    = w_out;                     // stash scores in w section
  float* partial  = (float*)d_ws;              // B*32*M floats = 1 MiB

  // A: scores — 16 lanes/row, 128 rows/block
  dim3 sgrid(Nn / (16 * SITERS), Bb);
  score_kernel<<<sgrid, 256, 0, stream>>>(memory, k, beta, score);
  // B: softmax/gate/shift/sharpen -> w (in place over score section)
  weight_kernel<<<Bb, 1024, 0, stream>>>(score, w_prev, g, s, gamma, w_out);
  // C+D: memory update + read reduction
  const size_t need = (size_t)Bb * 32 * Mm * sizeof(float);
  if (ws_size >= need) {
    rw_kernel<false><<<Bb * 32, 256, 0, stream>>>(memory, w_out, e, a, new_mem, partial);
    reduce_read_kernel<<<(Bb * Mm) / 256, 256, 0, stream>>>(partial, read_out);
  } else {
    hipMemsetAsync(read_out, 0, (size_t)Bb * Mm * sizeof(float), stream);
    rw_kernel<true><<<Bb * 32, 256, 0, stream>>>(memory, w_out, e, a, new_mem, read_out);
  }
}

// Round 9
// 148.615 us; speedup vs baseline: 1.1174x; 1.0705x over previous
//
#include <hip/hip_runtime.h>
#include <math.h>

#define Bb 64
#define Nn 8192
#define Mm 128
#define EPSf 1e-16f
#define COS_EPSf 1e-8f

typedef __attribute__((ext_vector_type(4))) float f32x4;

// ---------------- Kernel A: content-addressing scores ----------------
// 16 lanes per row, 2x float4 per lane (full 128-float row per 16-lane group).
// Block = 256 threads -> 16 rows/iter, SITERS=8 -> 128 rows per block.
// [R2 A/B: 16-lane/row + deep unroll vs 1-wave/row = -80 us]
#define SITERS 8
__global__ __launch_bounds__(256) void score_kernel(
    const float* __restrict__ memory, const float* __restrict__ k,
    const float* __restrict__ beta, float* score /* aliases w section */) {
  const int b = blockIdx.y;
  const int tid = threadIdx.x;
  const int q = tid & 15;        // position within row (16 lanes/row)
  const int rsub = tid >> 4;     // 0..15 row within the 16-row group
  const int row0 = blockIdx.x * (16 * SITERS);
  const size_t bbase = (size_t)b * Nn;

  // k fragment (+EPS) and ||k||^2 once
  const f32x4 ka = *(const f32x4*)(k + b * Mm + q * 4);
  const f32x4 kb = *(const f32x4*)(k + b * Mm + 64 + q * 4);
  float kf[8];
#pragma unroll
  for (int j = 0; j < 4; j++) { kf[j] = ka[j] + EPSf; kf[4 + j] = kb[j] + EPSf; }
  float sqk = 0.f;
#pragma unroll
  for (int j = 0; j < 8; j++) sqk += kf[j] * kf[j];
  sqk += __shfl_xor(sqk, 1); sqk += __shfl_xor(sqk, 2);
  sqk += __shfl_xor(sqk, 4); sqk += __shfl_xor(sqk, 8);
  const float bscale = beta[b] / fmaxf(sqrtf(sqk), COS_EPSf);

#pragma unroll 8
  for (int it = 0; it < SITERS; it++) {
    const int row = row0 + it * 16 + rsub;
    const float* rp = memory + (bbase + row) * Mm;
    const f32x4 ma = *(const f32x4*)(rp + q * 4);
    const f32x4 mb = *(const f32x4*)(rp + 64 + q * 4);
    float dot = 0.f, sqm = 0.f;
#pragma unroll
    for (int j = 0; j < 4; j++) {
      const float m0 = ma[j] + EPSf, m1 = mb[j] + EPSf;
      dot = fmaf(m0, kf[j], dot); dot = fmaf(m1, kf[4 + j], dot);
      sqm = fmaf(m0, m0, sqm);    sqm = fmaf(m1, m1, sqm);
    }
    dot += __shfl_xor(dot, 1); sqm += __shfl_xor(sqm, 1);
    dot += __shfl_xor(dot, 2); sqm += __shfl_xor(sqm, 2);
    dot += __shfl_xor(dot, 4); sqm += __shfl_xor(sqm, 4);
    dot += __shfl_xor(dot, 8); sqm += __shfl_xor(sqm, 8);
    if (q == 0) score[bbase + row] = bscale * dot / fmaxf(sqrtf(sqm), COS_EPSf);
  }
}

// ---------------- Kernel B: softmax + gate + circular shift + sharpen ----------------
__device__ __forceinline__ float block_sum16(float v, float* scratch) {
  const int lane = threadIdx.x & 63, wid = threadIdx.x >> 6;
  for (int o = 32; o; o >>= 1) v += __shfl_down(v, o);
  if (lane == 0) scratch[wid] = v;
  __syncthreads();
  if (threadIdx.x < 16) {
    v = scratch[threadIdx.x];
    for (int o = 8; o; o >>= 1) v += __shfl_down(v, o);
    if (threadIdx.x == 0) scratch[0] = v;
  }
  __syncthreads();
  v = scratch[0];
  __syncthreads();
  return v;
}

__device__ __forceinline__ float block_max16(float v, float* scratch) {
  const int lane = threadIdx.x & 63, wid = threadIdx.x >> 6;
  for (int o = 32; o; o >>= 1) v = fmaxf(v, __shfl_down(v, o));
  if (lane == 0) scratch[wid] = v;
  __syncthreads();
  if (threadIdx.x < 16) {
    v = scratch[threadIdx.x];
    for (int o = 8; o; o >>= 1) v = fmaxf(v, __shfl_down(v, o));
    if (threadIdx.x == 0) scratch[0] = v;
  }
  __syncthreads();
  v = scratch[0];
  __syncthreads();
  return v;
}

__global__ __launch_bounds__(1024) void weight_kernel(
    const float* score,                    // aliases w_out — all reads precede writes
    const float* __restrict__ w_prev, const float* __restrict__ g,
    const float* __restrict__ s, const float* __restrict__ gamma,
    float* w_out) {
  __shared__ float wg[Nn];          // 32 KiB
  __shared__ float scratch[16];
  const int b = blockIdx.x;
  const int tid = threadIdx.x;
  const int PT = Nn / 1024;         // 8 per thread

  float sc[PT];
  float lmax = -INFINITY;
#pragma unroll
  for (int i = 0; i < PT; i++) {
    sc[i] = score[b * Nn + tid + i * 1024];
    lmax = fmaxf(lmax, sc[i]);
  }
  const float bmax = block_max16(lmax, scratch);

  float lsum = 0.f;
#pragma unroll
  for (int i = 0; i < PT; i++) {
    sc[i] = expf(sc[i] - bmax);
    lsum += sc[i];
  }
  const float Z = block_sum16(lsum, scratch);
  const float invZ = 1.f / Z;

  const float gb = g[b];
  const float s0 = s[b * 3 + 0], s1 = s[b * 3 + 1], s2 = s[b * 3 + 2];
  const float gam = gamma[b];

#pragma unroll
  for (int i = 0; i < PT; i++) {
    const int n = tid + i * 1024;
    const float wr = sc[i] * invZ;
    wg[n] = gb * wr + (1.f - gb) * w_prev[b * Nn + n];
  }
  __syncthreads();

  float wp[PT];
  float psum = 0.f;
#pragma unroll
  for (int i = 0; i < PT; i++) {
    const int n = tid + i * 1024;
    const float wsv = s0 * wg[(n + Nn - 1) & (Nn - 1)] + s1 * wg[n] + s2 * wg[(n + 1) & (Nn - 1)];
    wp[i] = powf(wsv, gam);
    psum += wp[i];
  }
  const float S = block_sum16(psum, scratch) + EPSf;
  const float invS = 1.f / S;
#pragma unroll
  for (int i = 0; i < PT; i++) w_out[b * Nn + tid + i * 1024] = wp[i] * invS;
}

// ---------------- Kernel C: memory update + read partials ----------------
// 256 rows per block; thread t: m-quad = t&31, row-group = t>>5 (8 rows/iter).
// NT stores for new_memory (A/B: -25 us — write stream must not evict `memory`
// from MALL). REGULAR loads (A/B: NT loads +7 us — they forfeit the ~50% MALL
// hits from score's pass). Reverse block order (A/B: -2 us, LRU anti-thrash).
template <bool ATOMIC>
__global__ __launch_bounds__(256) void rw_kernel(
    const float* __restrict__ memory, const float* __restrict__ w,
    const float* __restrict__ e, const float* __restrict__ a,
    float* __restrict__ new_memory, float* __restrict__ out) {
  const int CH = 256;
  const int rbid = (int)gridDim.x - 1 - (int)blockIdx.x;   // reverse order
  const int b = rbid >> 5;             // 32 chunks per batch
  const int chunk = rbid & 31;
  const int tid = threadIdx.x;
  const int m4 = tid & 31;
  const int rowg = tid >> 5;

  const f32x4 e4 = *(const f32x4*)(e + b * Mm + m4 * 4);
  const f32x4 a4 = *(const f32x4*)(a + b * Mm + m4 * 4);
  f32x4 acc = {0.f, 0.f, 0.f, 0.f};
  const size_t bbase = (size_t)b * Nn;
  const int row0 = chunk * CH;

#pragma unroll 8
  for (int i = 0; i < CH / 8; i++) {
    const int n = row0 + i * 8 + rowg;
    const float wn = w[bbase + n];
    const f32x4 mv = *(const f32x4*)(memory + (bbase + n) * Mm + m4 * 4);
    // new = mv*(1 - wn*e) + wn*a = mv + wn*(a - e*mv)
    const f32x4 nm = mv + wn * (a4 - e4 * mv);
    __builtin_nontemporal_store(nm, (f32x4*)(new_memory + (bbase + n) * Mm + m4 * 4));
    acc += wn * mv;
  }

  __shared__ f32x4 red[256];
  red[tid] = acc;
  __syncthreads();
  for (int sh = 128; sh >= 32; sh >>= 1) {
    if (tid < sh) {
      const f32x4 o = red[tid + sh];
      red[tid] += o;
    }
    __syncthreads();
  }
  if (tid < 32) {
    const f32x4 r = red[tid];
    if (ATOMIC) {
      atomicAdd(&out[b * Mm + tid * 4 + 0], r[0]);
      atomicAdd(&out[b * Mm + tid * 4 + 1], r[1]);
      atomicAdd(&out[b * Mm + tid * 4 + 2], r[2]);
      atomicAdd(&out[b * Mm + tid * 4 + 3], r[3]);
    } else {
      *(f32x4*)(out + ((size_t)(b * 32 + chunk) * Mm) + tid * 4) = r;
    }
  }
}

// ---------------- Kernel D: fold chunk partials -> read[b,m] ----------------
__global__ __launch_bounds__(256) void reduce_read_kernel(
    const float* __restrict__ partial, float* __restrict__ readout) {
  const int t = blockIdx.x * 256 + threadIdx.x;  // [0, B*M)
  const int b = t >> 7, m = t & 127;
  const float* p = partial + (size_t)b * 32 * Mm + m;
  float sum = 0.f;
#pragma unroll
  for (int c = 0; c < 32; c++) sum += p[c * Mm];
  readout[t] = sum;
}

extern "C" void kernel_launch(void* const* d_in, const int* in_sizes, int n_in,
                              void* d_out, int out_size, void* d_ws, size_t ws_size,
                              hipStream_t stream) {
  const float* memory = (const float*)d_in[0];
  const float* k      = (const float*)d_in[1];
  const float* beta   = (const float*)d_in[2];
  const float* g      = (const float*)d_in[3];
  const float* s      = (const float*)d_in[4];
  const float* gamma  = (const float*)d_in[5];
  const float* w_prev = (const float*)d_in[6];
  const float* e      = (const float*)d_in[7];
  const float* a      = (const float*)d_in[8];

  float* out      = (float*)d_out;
  float* read_out = out;                       // B*M
  float* w_out    = out + Bb * Mm;             // B*N
  float* new_mem  = out + Bb * Mm + (size_t)Bb * Nn;  // B*N*M
  float* score    = w_out;                     // stash scores in w section
  float* partial  = (float*)d_ws;              // B*32*M floats = 1 MiB

  // A: scores — 16 lanes/row, 128 rows/block
  dim3 sgrid(Nn / (16 * SITERS), Bb);
  score_kernel<<<sgrid, 256, 0, stream>>>(memory, k, beta, score);
  // B: softmax/gate/shift/sharpen -> w (in place over score section)
  weight_kernel<<<Bb, 1024, 0, stream>>>(score, w_prev, g, s, gamma, w_out);
  // C+D: memory update + read reduction
  const size_t need = (size_t)Bb * 32 * Mm * sizeof(float);
  if (ws_size >= need) {
    rw_kernel<false><<<Bb * 32, 256, 0, stream>>>(memory, w_out, e, a, new_mem, partial);
    reduce_read_kernel<<<(Bb * Mm) / 256, 256, 0, stream>>>(partial, read_out);
  } else {
    hipMemsetAsync(read_out, 0, (size_t)Bb * Mm * sizeof(float), stream);
    rw_kernel<true><<<Bb * 32, 256, 0, stream>>>(memory, w_out, e, a, new_mem, read_out);
  }
}